// Round 14
// baseline (1185.054 us; speedup 1.0000x reference)
//
#include <hip/hip_runtime.h>

namespace {
constexpr int NWIN = 512;
constexpr int M    = 32;
constexpr int H    = 8;
constexpr int C    = 16;
constexpr int NSIG = 3;
constexpr int HC   = H * C;   // 128 floats per voxel row
constexpr int HB   = 4;       // heads per block (window split across 2 blocks)
constexpr int HBC  = HB * C;  // 64 floats of k/v staged per voxel
}

__device__ __forceinline__ float dot4(const float4& a, const float4& b) {
  return a.x * b.x + a.y * b.y + a.z * b.z + a.w * b.w;
}
__device__ __forceinline__ const float4* f4p(const float* p) {
  return reinterpret_cast<const float4*>(p);
}

struct RowBuf { float4 d[18]; };   // 9 gathered 32B row-slices (tq,tk,tv x 3 sig)

// Two blocks per window (4 heads each), 256 threads:
//   t -> hl = t>>6 (local head / wave), ch = (t>>5)&1 (channel half), i = t&31.
// Fused online-softmax j-loop, now SOFTWARE-PIPELINED depth-1: all 18 gathered
// loads of j+1 are issued into a second register buffer before consuming j.
// R4/R13 cycle arithmetic showed gathers ran fully serialized (~300cy each,
// 5.3K cy/j = 18x300); the 64-VGPR allocation couldn't hold in-flight loads.
// __launch_bounds__(256,2) raises the VGPR cap to 256 so A+B (144 VGPR) live
// in registers. Occupancy 2 blocks/CU — trading TLP (measured useless) for MLP.
__global__ __launch_bounds__(256, 2)
void win_attn(const float* __restrict__ qf, const float* __restrict__ kf,
              const float* __restrict__ vf, const float* __restrict__ qt,
              const float* __restrict__ kt, const float* __restrict__ vt,
              const int* __restrict__ toff, const int* __restrict__ widx,
              const int* __restrict__ tidx, float* __restrict__ out)
{
  const int w  = blockIdx.x >> 1;
  const int hb = (blockIdx.x & 1) * HB;   // head base for this block
  const int t  = threadIdx.x;
  const int hl = t >> 6;                  // local head 0..3 (wave id)
  const int ch = (t >> 5) & 1;            // channel half 0..1
  const int i  = t & 31;
  const int h  = hb + hl;                 // global head 0..7
  const int cb = ch * 8;                  // channel base within head
  const int hcb = h * C + cb;             // global row-slice offset
  const int lcb = hl * C + cb;            // LDS row-slice offset

  __shared__ float k_lds[M][HBC];          // 8 KB (4-head slice)
  __shared__ float v_lds[M][HBC];          // 8 KB
  __shared__ int   tid_lds[M * NSIG * M];  // 12 KB, [(j*3+s)*32 + i]
  __shared__ int   vox_lds[M];
  __shared__ int   off_lds[NSIG];

  if (t < M)    vox_lds[t] = widx[w * M + t];
  if (t < NSIG) off_lds[t] = toff[t];
  __syncthreads();

  // Stage the block's 4-head slice of k,v: 512 float4 per table.
  #pragma unroll
  for (int r = 0; r < 2; ++r) {
    const int flat = t + 256 * r;        // [0,512)
    const int j    = flat >> 4;          // voxel 0..31
    const int f4i  = (flat & 15) * 4;    // float index within 64-float slice
    const int goff = vox_lds[j] * HC + hb * C + f4i;
    *reinterpret_cast<float4*>(&k_lds[j][f4i]) = *f4p(kf + goff);
    *reinterpret_cast<float4*>(&v_lds[j][f4i]) = *f4p(vf + goff);
  }
  // Stage table_idx (global layout [i][j][s]) transposed to [(j*3+s)*32+i].
  #pragma unroll
  for (int r = 0; r < 12; ++r) {
    const int g   = t + 256 * r;         // [0,3072)
    const int ii  = g / 96;
    const int rem = g - ii * 96;
    const int jj  = rem / 3;
    const int ss  = rem - jj * 3;
    tid_lds[(jj * NSIG + ss) * M + ii] = tidx[w * (M * M * NSIG) + g];
  }

  // q half-slice for (i,h,ch): 8 floats in registers.
  const int vox_i = vox_lds[i];
  const float* qrow = qf + vox_i * HC + hcb;
  const float4 q0 = f4p(qrow)[0], q1 = f4p(qrow)[1];
  const int offs[NSIG] = { off_lds[0], off_lds[1], off_lds[2] };
  __syncthreads();

  float m    = -INFINITY;
  float ssum = 0.f;
  float oacc[8];
  #pragma unroll
  for (int c = 0; c < 8; ++c) oacc[c] = 0.f;

  // Issue all 18 gathered loads for row-set j into buffer b.
  auto load_rows = [&](RowBuf& b, int j) {
    #pragma unroll
    for (int s = 0; s < NSIG; ++s) {
      const int row = offs[s] + tid_lds[(j * NSIG + s) * M + i];
      const float* bq = qt + row * HC + hcb;
      const float* bk = kt + row * HC + hcb;
      const float* bv = vt + row * HC + hcb;
      b.d[s * 6 + 0] = f4p(bq)[0];  b.d[s * 6 + 1] = f4p(bq)[1];
      b.d[s * 6 + 2] = f4p(bk)[0];  b.d[s * 6 + 3] = f4p(bk)[1];
      b.d[s * 6 + 4] = f4p(bv)[0];  b.d[s * 6 + 5] = f4p(bv)[1];
    }
  };

  // Consume buffer b for step j: logit -> online softmax -> PV accumulate.
  auto consume = [&](const RowBuf& b, int j) {
    const float* krow = &k_lds[j][lcb];
    const float4 k0 = f4p(krow)[0], k1 = f4p(krow)[1];
    const float* vrow = &v_lds[j][lcb];
    const float4 vv0 = f4p(vrow)[0], vv1 = f4p(vrow)[1];

    float logit = dot4(q0, k0) + dot4(q1, k1);
    #pragma unroll
    for (int s = 0; s < NSIG; ++s) {
      logit += dot4(q0, b.d[s * 6 + 0]) + dot4(q1, b.d[s * 6 + 1])
             + dot4(k0, b.d[s * 6 + 2]) + dot4(k1, b.d[s * 6 + 3]);
    }
    logit += __shfl_xor(logit, 32);   // combine the two channel halves

    const float mnew  = fmaxf(m, logit);
    const float scale = expf(m - mnew);   // ==0 at j=0 (m=-inf), exact
    const float e     = expf(logit - mnew);
    ssum = ssum * scale + e;
    m    = mnew;

    float4 sv0 = vv0, sv1 = vv1;          // v + the 3 table-v slices
    #pragma unroll
    for (int s = 0; s < NSIG; ++s) {
      sv0.x += b.d[s * 6 + 4].x;  sv0.y += b.d[s * 6 + 4].y;
      sv0.z += b.d[s * 6 + 4].z;  sv0.w += b.d[s * 6 + 4].w;
      sv1.x += b.d[s * 6 + 5].x;  sv1.y += b.d[s * 6 + 5].y;
      sv1.z += b.d[s * 6 + 5].z;  sv1.w += b.d[s * 6 + 5].w;
    }
    oacc[0] = oacc[0] * scale + e * sv0.x;
    oacc[1] = oacc[1] * scale + e * sv0.y;
    oacc[2] = oacc[2] * scale + e * sv0.z;
    oacc[3] = oacc[3] * scale + e * sv0.w;
    oacc[4] = oacc[4] * scale + e * sv1.x;
    oacc[5] = oacc[5] * scale + e * sv1.y;
    oacc[6] = oacc[6] * scale + e * sv1.z;
    oacc[7] = oacc[7] * scale + e * sv1.w;
  };

  // Depth-1 pipeline over j: ping-pong named buffers, fully unrolled (static
  // indexing only -> registers, no scratch).
  RowBuf A, B;
  load_rows(A, 0);
  #pragma unroll
  for (int jj = 0; jj < M / 2; ++jj) {
    load_rows(B, 2 * jj + 1);
    consume(A, 2 * jj);
    if (jj < M / 2 - 1) load_rows(A, 2 * jj + 2);
    consume(B, 2 * jj + 1);
  }

  const float inv = 1.0f / ssum;
  float* orow = out + vox_i * HC + hcb;
  float4 o0, o1;
  o0.x = oacc[0] * inv;  o0.y = oacc[1] * inv;
  o0.z = oacc[2] * inv;  o0.w = oacc[3] * inv;
  o1.x = oacc[4] * inv;  o1.y = oacc[5] * inv;
  o1.z = oacc[6] * inv;  o1.w = oacc[7] * inv;
  reinterpret_cast<float4*>(orow)[0] = o0;
  reinterpret_cast<float4*>(orow)[1] = o1;
}

extern "C" void kernel_launch(void* const* d_in, const int* in_sizes, int n_in,
                              void* d_out, int out_size, void* d_ws, size_t ws_size,
                              hipStream_t stream) {
  (void)in_sizes; (void)n_in; (void)d_ws; (void)ws_size; (void)out_size;
  const float* qf  = (const float*)d_in[0];
  const float* kf  = (const float*)d_in[1];
  const float* vf  = (const float*)d_in[2];
  const float* qt  = (const float*)d_in[3];
  const float* kt  = (const float*)d_in[4];
  const float* vt  = (const float*)d_in[5];
  const int*  toff = (const int*)d_in[6];
  const int*  widx = (const int*)d_in[7];
  const int*  tidx = (const int*)d_in[8];
  float* out = (float*)d_out;
  win_attn<<<NWIN * 2, 256, 0, stream>>>(qf, kf, vf, qt, kt, vt, toff, widx, tidx, out);
}

// Round 16
// 1010.648 us; speedup vs baseline: 1.1726x; 1.1726x over previous
//
#include <hip/hip_runtime.h>

namespace {
constexpr int NWIN = 512;
constexpr int M    = 32;
constexpr int H    = 8;
constexpr int C    = 16;
constexpr int NSIG = 3;
constexpr int HC   = H * C;   // 128 floats per voxel row
constexpr int HB   = 4;       // heads per block (window split across 2 blocks)
constexpr int HBC  = HB * C;  // 64 floats of k/v staged per voxel
constexpr int MS   = 11;      // merge slot stride (odd -> conflict-free)
}

__device__ __forceinline__ float dot4(const float4& a, const float4& b) {
  return a.x * b.x + a.y * b.y + a.z * b.z + a.w * b.w;
}
__device__ __forceinline__ const float4* f4p(const float* p) {
  return reinterpret_cast<const float4*>(p);
}

// Two blocks per window (4 heads each), 512 threads = 8 waves:
//   wave = t>>6 -> (hl = wave>>1: local head, jh = wave&1: j-half)
//   lane -> ch = (t>>5)&1 (channel half), i = t&31 (query voxel).
// Each thread runs the R13-proven fused online-softmax body over its 16 j's;
// the jh=0/1 partials (m, ssum, oacc[8]) merge through LDS at the end.
// Purpose: double waves/CU to 32 (R13 was 16) at unchanged VGPR=64 to
// disambiguate chain-latency-bound (expect ~2x) vs TA-touch-bound (flat).
// R14's register double-buffer spilled to scratch (WRITE 1.4GB) - reverted.
__global__ __launch_bounds__(512, 8)
void win_attn(const float* __restrict__ qf, const float* __restrict__ kf,
              const float* __restrict__ vf, const float* __restrict__ qt,
              const float* __restrict__ kt, const float* __restrict__ vt,
              const int* __restrict__ toff, const int* __restrict__ widx,
              const int* __restrict__ tidx, float* __restrict__ out)
{
  const int w    = blockIdx.x >> 1;
  const int hb   = (blockIdx.x & 1) * HB;  // head base for this block
  const int t    = threadIdx.x;
  const int wave = t >> 6;
  const int hl   = wave >> 1;              // local head 0..3
  const int jh   = wave & 1;               // j-half 0..1
  const int ch   = (t >> 5) & 1;           // channel half 0..1
  const int i    = t & 31;
  const int h    = hb + hl;                // global head 0..7
  const int cb   = ch * 8;                 // channel base within head
  const int hcb  = h * C + cb;             // global row-slice float offset
  const int lcb  = hl * C + cb;            // LDS row-slice float offset

  __shared__ float k_lds[M][HBC];           // 8 KB (4-head slice)
  __shared__ float v_lds[M][HBC];           // 8 KB
  __shared__ int   tid_lds[M * NSIG * M];   // 12 KB, [(j*3+s)*32 + i]
  __shared__ float merge_lds[4 * 2 * 32 * MS]; // 11 KB partial-softmax merge
  __shared__ int   vox_lds[M];
  __shared__ int   off_lds[NSIG];

  if (t < M)    vox_lds[t] = widx[w * M + t];
  if (t < NSIG) off_lds[t] = toff[t];
  __syncthreads();

  // Stage the block's 4-head slice of k,v: 512 float4 per table, one each.
  {
    const int j   = t >> 4;              // voxel 0..31
    const int f4i = (t & 15) * 4;        // float index within 64-float slice
    const int goff = vox_lds[j] * HC + hb * C + f4i;
    *reinterpret_cast<float4*>(&k_lds[j][f4i]) = *f4p(kf + goff);
    *reinterpret_cast<float4*>(&v_lds[j][f4i]) = *f4p(vf + goff);
  }
  // Stage table_idx (global layout [i][j][s]) transposed to [(j*3+s)*32+i].
  #pragma unroll
  for (int r = 0; r < 6; ++r) {
    const int g   = t + 512 * r;         // [0,3072)
    const int ii  = g / 96;
    const int rem = g - ii * 96;
    const int jj  = rem / 3;
    const int ss  = rem - jj * 3;
    tid_lds[(jj * NSIG + ss) * M + ii] = tidx[w * (M * M * NSIG) + g];
  }

  // q half-slice for (i,h,ch): 8 floats in registers.
  const int vox_i = vox_lds[i];
  const float* qrow = qf + vox_i * HC + hcb;
  const float4 q0 = f4p(qrow)[0], q1 = f4p(qrow)[1];
  const int offs[NSIG] = { off_lds[0], off_lds[1], off_lds[2] };
  __syncthreads();

  // ---- Fused j-loop over this wave's 16 j's (R13 body, unchanged) ----
  float m    = -INFINITY;
  float ssum = 0.f;
  float oacc[8];
  #pragma unroll
  for (int c = 0; c < 8; ++c) oacc[c] = 0.f;

  const int jbase = jh * (M / 2);
  #pragma unroll
  for (int jr = 0; jr < M / 2; ++jr) {
    const int j = jbase + jr;
    const float* krow = &k_lds[j][lcb];
    const float4 k0 = f4p(krow)[0], k1 = f4p(krow)[1];
    const float4 vv0 = f4p(&v_lds[j][lcb])[0];
    const float4 vv1 = f4p(&v_lds[j][lcb])[1];

    float logit = dot4(q0, k0) + dot4(q1, k1);
    float4 tv0[NSIG], tv1[NSIG];
    #pragma unroll
    for (int s = 0; s < NSIG; ++s) {
      const int row = offs[s] + tid_lds[(j * NSIG + s) * M + i];
      const float* base = qt + row * HC + hcb;
      const float4 a0 = f4p(base)[0], a1 = f4p(base)[1];
      const float* kbase = kt + row * HC + hcb;
      const float4 b0 = f4p(kbase)[0], b1 = f4p(kbase)[1];
      const float* vbase = vt + row * HC + hcb;
      tv0[s] = f4p(vbase)[0];
      tv1[s] = f4p(vbase)[1];
      logit += dot4(q0, a0) + dot4(q1, a1) + dot4(k0, b0) + dot4(k1, b1);
    }
    logit += __shfl_xor(logit, 32);   // combine the two channel halves

    const float mnew  = fmaxf(m, logit);
    const float scale = expf(m - mnew);   // ==0 at first iter (m=-inf), exact
    const float e     = expf(logit - mnew);
    ssum = ssum * scale + e;
    m    = mnew;

    float4 sv0 = tv0[0], sv1 = tv1[0];    // v + the 3 table-v slices
    sv0.x += tv0[1].x + tv0[2].x + vv0.x;  sv0.y += tv0[1].y + tv0[2].y + vv0.y;
    sv0.z += tv0[1].z + tv0[2].z + vv0.z;  sv0.w += tv0[1].w + tv0[2].w + vv0.w;
    sv1.x += tv1[1].x + tv1[2].x + vv1.x;  sv1.y += tv1[1].y + tv1[2].y + vv1.y;
    sv1.z += tv1[1].z + tv1[2].z + vv1.z;  sv1.w += tv1[1].w + tv1[2].w + vv1.w;

    oacc[0] = oacc[0] * scale + e * sv0.x;
    oacc[1] = oacc[1] * scale + e * sv0.y;
    oacc[2] = oacc[2] * scale + e * sv0.z;
    oacc[3] = oacc[3] * scale + e * sv0.w;
    oacc[4] = oacc[4] * scale + e * sv1.x;
    oacc[5] = oacc[5] * scale + e * sv1.y;
    oacc[6] = oacc[6] * scale + e * sv1.z;
    oacc[7] = oacc[7] * scale + e * sv1.w;
  }

  // ---- Merge the two j-half partials through LDS ----
  const int slot = ((hl * 2 + ch) * 32 + i) * MS;
  if (jh == 1) {
    merge_lds[slot + 0] = m;
    merge_lds[slot + 1] = ssum;
    #pragma unroll
    for (int c = 0; c < 8; ++c) merge_lds[slot + 2 + c] = oacc[c];
  }
  __syncthreads();
  if (jh == 0) {
    const float m1 = merge_lds[slot + 0];
    const float s1 = merge_lds[slot + 1];
    const float Mx = fmaxf(m, m1);
    const float a  = expf(m - Mx);
    const float b  = expf(m1 - Mx);
    const float S  = ssum * a + s1 * b;
    const float inv = 1.0f / S;
    float* orow = out + vox_i * HC + hcb;
    float4 o0, o1;
    o0.x = (oacc[0] * a + merge_lds[slot + 2] * b) * inv;
    o0.y = (oacc[1] * a + merge_lds[slot + 3] * b) * inv;
    o0.z = (oacc[2] * a + merge_lds[slot + 4] * b) * inv;
    o0.w = (oacc[3] * a + merge_lds[slot + 5] * b) * inv;
    o1.x = (oacc[4] * a + merge_lds[slot + 6] * b) * inv;
    o1.y = (oacc[5] * a + merge_lds[slot + 7] * b) * inv;
    o1.z = (oacc[6] * a + merge_lds[slot + 8] * b) * inv;
    o1.w = (oacc[7] * a + merge_lds[slot + 9] * b) * inv;
    reinterpret_cast<float4*>(orow)[0] = o0;
    reinterpret_cast<float4*>(orow)[1] = o1;
  }
}

extern "C" void kernel_launch(void* const* d_in, const int* in_sizes, int n_in,
                              void* d_out, int out_size, void* d_ws, size_t ws_size,
                              hipStream_t stream) {
  (void)in_sizes; (void)n_in; (void)d_ws; (void)ws_size; (void)out_size;
  const float* qf  = (const float*)d_in[0];
  const float* kf  = (const float*)d_in[1];
  const float* vf  = (const float*)d_in[2];
  const float* qt  = (const float*)d_in[3];
  const float* kt  = (const float*)d_in[4];
  const float* vt  = (const float*)d_in[5];
  const int*  toff = (const int*)d_in[6];
  const int*  widx = (const int*)d_in[7];
  const int*  tidx = (const int*)d_in[8];
  float* out = (float*)d_out;
  win_attn<<<NWIN * 2, 512, 0, stream>>>(qf, kf, vf, qt, kt, vt, toff, widx, tidx, out);
}